// Round 1
// baseline (1774.334 us; speedup 1.0000x reference)
//
#include <hip/hip_runtime.h>
#include <math.h>

#define D   128
#define DE  128
#define DT  100
#define FF  10
#define BB  512
#define GG  1536
#define NN1 15360
#define NNODES 500000

constexpr int KVDIM = D + DE + DT; // 356
constexpr int QDIM  = D + DT;      // 228

// ---------------------------------------------------------------------------
// Kernel 1: copy memory -> out_mem, memory_ts -> out_ts (float4 grid-stride)
// ---------------------------------------------------------------------------
__global__ void copy_kernel(const float4* __restrict__ mem,
                            const float4* __restrict__ ts,
                            float4* __restrict__ out_mem,
                            float4* __restrict__ out_ts) {
    const long nmem = (long)NNODES * D / 4;   // 16,000,000
    const long nts  = NNODES / 4;             // 125,000
    long stride = (long)gridDim.x * blockDim.x;
    for (long i = (long)blockIdx.x * blockDim.x + threadIdx.x;
         i < nmem + nts; i += stride) {
        if (i < nmem) out_mem[i] = mem[i];
        else          out_ts[i - nmem] = ts[i - nmem];
    }
}

// ---------------------------------------------------------------------------
// Kernel 2: fused attention (used for both layers).
// 4 rows per block, 256 threads = 2 row-groups x 128 cols.
// Wave layout: wave w handles (rg = w>>1, head = w&1) exactly.
// ---------------------------------------------------------------------------
__global__ __launch_bounds__(256) void attn_kernel(
    int N,
    const float* __restrict__ dst_feat,   // N x D
    const float* __restrict__ src_feat,   // N x F x D
    const int*   __restrict__ dst_nodes,  // N
    const int*   __restrict__ src_nodes,  // N x F
    const float* __restrict__ dst_ts,     // N
    const float* __restrict__ src_ts,     // N x F
    const float* __restrict__ edge_feat,  // N x F x DE
    const float* __restrict__ memory,     // NNODES x D
    const float* __restrict__ Wq, const float* __restrict__ bq,  // 228x128, 128
    const float* __restrict__ Wk, const float* __restrict__ bk,  // 356x128
    const float* __restrict__ Wv, const float* __restrict__ bv,  // 356x128
    const float* __restrict__ Wo, const float* __restrict__ bo,  // 256x128
    const float* __restrict__ tw, const float* __restrict__ tb,  // 100
    const float* __restrict__ add_in,     // optional h_root1 (N x D) or null
    float* __restrict__ out)              // N x D
{
    __shared__ float kv_lds[4 * FF * KVDIM];  // 56,960 B
    __shared__ float dh_lds[4][D];
    __shared__ float qt_lds[DT];
    __shared__ float sc_lds[4][2][FF];
    __shared__ float o_lds[4][D];

    const int tid  = threadIdx.x;
    const int j    = tid & 127;
    const int rg   = tid >> 7;       // 0 or 1
    const int base = blockIdx.x * 4;
    const int head = j >> 6;         // 0 or 1 (uniform per wave)

    if (tid < DT) qt_lds[tid] = cosf(tb[tid]);

    // dst_h = dst_feat + memory[dst_nodes]
    for (int idx = tid; idx < 4 * D; idx += 256) {
        int r = idx >> 7, c = idx & 127;
        int row = base + r;
        if (row < N)
            dh_lds[r][c] = dst_feat[(long)row * D + c] +
                           memory[(long)dst_nodes[row] * D + c];
    }

    // kv = [src_h | edge_feat | tfeat]
    for (int idx = tid; idx < 4 * FF * KVDIM; idx += 256) {
        int r   = idx / (FF * KVDIM);
        int rem = idx - r * (FF * KVDIM);
        int f   = rem / KVDIM;
        int c   = rem - f * KVDIM;
        int row = base + r;
        if (row >= N) continue;
        float val;
        if (c < D) {
            val = src_feat[((long)row * FF + f) * D + c] +
                  memory[(long)src_nodes[row * FF + f] * D + c];
        } else if (c < D + DE) {
            val = edge_feat[((long)row * FF + f) * DE + (c - D)];
        } else {
            float dt_ = dst_ts[row] - src_ts[row * FF + f];
            int tc = c - (D + DE);
            val = cosf(dt_ * tw[tc] + tb[tc]);
        }
        kv_lds[idx] = val;
    }
    __syncthreads();

    const int r0 = rg * 2;  // first of my two rows

    // q for my two rows (includes bias)
    float q0 = bq[j], q1 = bq[j];
    for (int c = 0; c < D; ++c) {
        float wq = Wq[c * D + j];
        q0 += dh_lds[r0][c] * wq;
        q1 += dh_lds[r0 + 1][c] * wq;
    }
    {
        float qadd = 0.f;
        for (int c = 0; c < DT; ++c) qadd += qt_lds[c] * Wq[(D + c) * D + j];
        q0 += qadd; q1 += qadd;
    }

    // k/v projection: acc[r2][f] over 356-dim contraction
    float acc_k[2][FF], acc_v[2][FF];
    #pragma unroll
    for (int r2 = 0; r2 < 2; ++r2)
        #pragma unroll
        for (int f = 0; f < FF; ++f) { acc_k[r2][f] = 0.f; acc_v[r2][f] = 0.f; }

    for (int c = 0; c < KVDIM; c += 4) {
        float wk0 = Wk[(c + 0) * D + j], wk1 = Wk[(c + 1) * D + j];
        float wk2 = Wk[(c + 2) * D + j], wk3 = Wk[(c + 3) * D + j];
        float wv0 = Wv[(c + 0) * D + j], wv1 = Wv[(c + 1) * D + j];
        float wv2 = Wv[(c + 2) * D + j], wv3 = Wv[(c + 3) * D + j];
        #pragma unroll
        for (int r2 = 0; r2 < 2; ++r2) {
            #pragma unroll
            for (int f = 0; f < FF; ++f) {
                const float4 kvv = *(const float4*)&kv_lds[((r0 + r2) * FF + f) * KVDIM + c];
                acc_k[r2][f] += kvv.x * wk0 + kvv.y * wk1 + kvv.z * wk2 + kvv.w * wk3;
                acc_v[r2][f] += kvv.x * wv0 + kvv.y * wv1 + kvv.z * wv2 + kvv.w * wv3;
            }
        }
    }

    const float bkj = bk[j], bvj = bv[j];
    const float qv[2] = {q0, q1};

    // scores: per (r2, f) reduce q*k over the 64 lanes of this wave (one head)
    #pragma unroll
    for (int r2 = 0; r2 < 2; ++r2) {
        #pragma unroll
        for (int f = 0; f < FF; ++f) {
            float val = qv[r2] * (acc_k[r2][f] + bkj);
            for (int off = 32; off > 0; off >>= 1) val += __shfl_xor(val, off, 64);
            if ((tid & 63) == 0) sc_lds[r0 + r2][head][f] = val;
        }
    }
    __syncthreads();

    // softmax over f (scale 1/8), 8 threads handle (row, head) pairs
    if (tid < 8) {
        int r = tid >> 1, h = tid & 1;
        float s[FF], m = -1e30f;
        #pragma unroll
        for (int f = 0; f < FF; ++f) { s[f] = sc_lds[r][h][f] * 0.125f; m = fmaxf(m, s[f]); }
        float sum = 0.f;
        #pragma unroll
        for (int f = 0; f < FF; ++f) { s[f] = expf(s[f] - m); sum += s[f]; }
        float inv = 1.f / sum;
        #pragma unroll
        for (int f = 0; f < FF; ++f) sc_lds[r][h][f] = s[f] * inv;
    }
    __syncthreads();

    // o[row][j] = sum_f a[row][head][f] * v[row][f][j]
    #pragma unroll
    for (int r2 = 0; r2 < 2; ++r2) {
        float o = 0.f;
        #pragma unroll
        for (int f = 0; f < FF; ++f) o += sc_lds[r0 + r2][head][f] * (acc_v[r2][f] + bvj);
        o_lds[r0 + r2][j] = o;
    }
    __syncthreads();

    // out = relu([dst_h, o] @ Wo + bo); optionally (x + add_in) * 0.5
    float a0 = bo[j], a1 = bo[j];
    for (int c = 0; c < D; ++c) {
        float w = Wo[c * D + j];
        a0 += dh_lds[r0][c] * w;
        a1 += dh_lds[r0 + 1][c] * w;
    }
    for (int c = 0; c < D; ++c) {
        float w = Wo[(D + c) * D + j];
        a0 += o_lds[r0][c] * w;
        a1 += o_lds[r0 + 1][c] * w;
    }
    {
        int row = base + r0;
        if (row < N) {
            float v = fmaxf(a0, 0.f);
            if (add_in) v = (v + add_in[(long)row * D + j]) * 0.5f;
            out[(long)row * D + j] = v;
        }
        row = base + r0 + 1;
        if (row < N) {
            float v = fmaxf(a1, 0.f);
            if (add_in) v = (v + add_in[(long)row * D + j]) * 0.5f;
            out[(long)row * D + j] = v;
        }
    }
}

// ---------------------------------------------------------------------------
// Kernel 3: h_root1[g,d] = mean_f h1[g*10+f, d]   (must run BEFORE e2n)
// ---------------------------------------------------------------------------
__global__ void hroot_kernel(const float* __restrict__ h1, float* __restrict__ out) {
    int idx = blockIdx.x * blockDim.x + threadIdx.x;
    if (idx >= GG * D) return;
    int g = idx >> 7, d = idx & 127;
    float s = 0.f;
    #pragma unroll
    for (int f = 0; f < FF; ++f) s += h1[(long)(g * FF + f) * D + d];
    out[idx] = s / 10.0f;
}

// ---------------------------------------------------------------------------
// Kernel 4: next_src = h1 @ e2n_W + e2n_b   (in-place on h1: row-independent)
// ---------------------------------------------------------------------------
__global__ __launch_bounds__(256) void e2n_kernel(
    float* __restrict__ h1, const float* __restrict__ W, const float* __restrict__ b) {
    __shared__ float h_lds[4][D];
    const int tid = threadIdx.x, j = tid & 127, rg = tid >> 7;
    const int base = blockIdx.x * 4;
    for (int idx = tid; idx < 4 * D; idx += 256)
        h_lds[idx >> 7][idx & 127] = h1[(long)(base + (idx >> 7)) * D + (idx & 127)];
    __syncthreads();
    float a0 = b[j], a1 = b[j];
    const int r0 = rg * 2;
    for (int c = 0; c < D; ++c) {
        float w = W[c * D + j];
        a0 += h_lds[r0][c] * w;
        a1 += h_lds[r0 + 1][c] * w;
    }
    h1[(long)(base + r0) * D + j]     = a0;
    h1[(long)(base + r0 + 1) * D + j] = a1;
}

// ---------------------------------------------------------------------------
// Kernel 5: GRU memory update (1024 rows), 2 rows/block, 384 threads
// x = [msg(128) | prev_mem(128) | tfeat(100) | ef(128)] = 484
// ---------------------------------------------------------------------------
__global__ __launch_bounds__(384) void gru_kernel(
    const int*   __restrict__ dst_nodes0,
    const float* __restrict__ root_ts,
    const float* __restrict__ root_edge_feat,
    const float* __restrict__ memory,
    const float* __restrict__ memory_ts,
    const float* __restrict__ h_total,
    const float* __restrict__ mt_w, const float* __restrict__ mt_b,
    const float* __restrict__ Wih,  const float* __restrict__ Whh,
    const float* __restrict__ bih,  const float* __restrict__ bhh,
    float* __restrict__ new_mem)
{
    __shared__ float x_lds[2][484];
    __shared__ float gi_lds[2][384];
    __shared__ float gh_lds[2][384];
    const int tid = threadIdx.x;
    const int base = blockIdx.x * 2;

    for (int idx = tid; idx < 2 * 484; idx += 384) {
        int r = idx / 484, c = idx - r * 484;
        int row = base + r;
        int node = dst_nodes0[row];
        float v;
        if (c < 128)      v = h_total[(long)row * D + c];
        else if (c < 256) v = memory[(long)node * D + (c - 128)];
        else if (c < 356) {
            float dt_ = fmaxf(root_ts[row & 511] - memory_ts[node], 0.f);
            v = cosf(dt_ * mt_w[c - 256] + mt_b[c - 256]);
        } else            v = root_edge_feat[(long)(row & 511) * DE + (c - 356)];
        x_lds[r][c] = v;
    }
    __syncthreads();

    {
        float g0 = bih[tid], g1 = bih[tid];
        for (int c = 0; c < 484; ++c) {
            float w = Wih[c * 384 + tid];
            g0 += x_lds[0][c] * w;
            g1 += x_lds[1][c] * w;
        }
        gi_lds[0][tid] = g0; gi_lds[1][tid] = g1;
        float h0 = bhh[tid], h1_ = bhh[tid];
        for (int c = 0; c < 128; ++c) {
            float w = Whh[c * 384 + tid];
            h0  += x_lds[0][128 + c] * w;
            h1_ += x_lds[1][128 + c] * w;
        }
        gh_lds[0][tid] = h0; gh_lds[1][tid] = h1_;
    }
    __syncthreads();

    if (tid < 256) {
        int r = tid >> 7, d = tid & 127;
        float ir = gi_lds[r][d], iz = gi_lds[r][128 + d], in_ = gi_lds[r][256 + d];
        float hr = gh_lds[r][d], hz = gh_lds[r][128 + d], hn  = gh_lds[r][256 + d];
        float rr = 1.f / (1.f + expf(-(ir + hr)));
        float zz = 1.f / (1.f + expf(-(iz + hz)));
        float nn = tanhf(in_ + rr * hn);
        float h  = x_lds[r][128 + d];
        new_mem[(long)(base + r) * D + d] = (1.f - zz) * nn + zz * h;
    }
}

// ---------------------------------------------------------------------------
// Kernel 6: scatter new_mem into out_mem with last-occurrence-wins (np semantics)
// ---------------------------------------------------------------------------
__global__ __launch_bounds__(128) void scatter_kernel(
    const int*   __restrict__ dst_nodes0,
    const float* __restrict__ root_ts,
    const float* __restrict__ new_mem,
    float* __restrict__ out_mem,
    float* __restrict__ out_ts)
{
    __shared__ int lose;
    const int i = blockIdx.x;     // 0..1023
    const int tid = threadIdx.x;
    if (tid == 0) lose = 0;
    __syncthreads();
    const int node = dst_nodes0[i];
    for (int jj = i + 1 + tid; jj < 1024; jj += 128)
        if (dst_nodes0[jj] == node) lose = 1;
    __syncthreads();
    if (!lose) {
        out_mem[(long)node * D + tid] = new_mem[(long)i * D + tid];
        if (tid == 0) out_ts[node] = root_ts[i & 511];
    }
}

// ---------------------------------------------------------------------------
// Kernel 7: edge predictor, 4 rows/block, 128 threads
// ---------------------------------------------------------------------------
__global__ __launch_bounds__(128) void ep_kernel(
    const float* __restrict__ h_total,
    const float* __restrict__ Wsrc, const float* __restrict__ bsrc,
    const float* __restrict__ Wdst, const float* __restrict__ bdst,
    const float* __restrict__ Wout, const float* __restrict__ bout,
    float* __restrict__ out_pos, float* __restrict__ out_neg)
{
    __shared__ float hs[4][D], hd[4][D], hn[4][D];
    __shared__ float part[4][2][2];
    const int tid = threadIdx.x;
    const int base = blockIdx.x * 4;
    for (int idx = tid; idx < 4 * D; idx += 128) {
        int r = idx >> 7, c = idx & 127;
        hs[r][c] = h_total[(long)(base + r) * D + c];
        hd[r][c] = h_total[(long)(512 + base + r) * D + c];
        hn[r][c] = h_total[(long)(1024 + base + r) * D + c];
    }
    __syncthreads();
    const int j = tid;
    const float wout = Wout[j];
    for (int r = 0; r < 4; ++r) {
        float s = bsrc[j], dp = bdst[j], dn = bdst[j];
        for (int c = 0; c < D; ++c) {
            float ws = Wsrc[c * D + j], wd = Wdst[c * D + j];
            s  += hs[r][c] * ws;
            dp += hd[r][c] * wd;
            dn += hn[r][c] * wd;
        }
        float pv = fmaxf(s + dp, 0.f) * wout;
        float nv = fmaxf(s + dn, 0.f) * wout;
        for (int off = 32; off > 0; off >>= 1) {
            pv += __shfl_xor(pv, off, 64);
            nv += __shfl_xor(nv, off, 64);
        }
        if ((tid & 63) == 0) { part[r][0][tid >> 6] = pv; part[r][1][tid >> 6] = nv; }
    }
    __syncthreads();
    if (tid < 4) {
        out_pos[base + tid] = part[tid][0][0] + part[tid][0][1] + bout[0];
        out_neg[base + tid] = part[tid][1][0] + part[tid][1][1] + bout[0];
    }
}

// ---------------------------------------------------------------------------
extern "C" void kernel_launch(void* const* d_in, const int* in_sizes, int n_in,
                              void* d_out, int out_size, void* d_ws, size_t ws_size,
                              hipStream_t stream) {
    const int*   dst_nodes0     = (const int*)d_in[0];
    const int*   src_nodes0     = (const int*)d_in[1];
    const float* dst_feat0      = (const float*)d_in[2];
    const float* dst_ts0        = (const float*)d_in[3];
    const float* src_ts0        = (const float*)d_in[4];
    const float* edge_feat0     = (const float*)d_in[5];
    const int*   dst_nodes1     = (const int*)d_in[6];
    const int*   src_nodes1     = (const int*)d_in[7];
    const float* dst_feat1      = (const float*)d_in[8];
    const float* src_feat1      = (const float*)d_in[9];
    const float* dst_ts1        = (const float*)d_in[10];
    const float* src_ts1        = (const float*)d_in[11];
    const float* edge_feat1     = (const float*)d_in[12];
    const float* root_ts        = (const float*)d_in[13];
    const float* root_edge_feat = (const float*)d_in[14];
    const float* memory         = (const float*)d_in[15];
    const float* memory_ts      = (const float*)d_in[16];
    const float* Wq  = (const float*)d_in[17];
    const float* bq  = (const float*)d_in[18];
    const float* Wk  = (const float*)d_in[19];
    const float* bk  = (const float*)d_in[20];
    const float* Wv  = (const float*)d_in[21];
    const float* bv  = (const float*)d_in[22];
    const float* Wo  = (const float*)d_in[23];
    const float* bo  = (const float*)d_in[24];
    const float* tw  = (const float*)d_in[25];
    const float* tb  = (const float*)d_in[26];
    const float* e2n_W = (const float*)d_in[27];
    const float* e2n_b = (const float*)d_in[28];
    const float* mt_w  = (const float*)d_in[29];
    const float* mt_b  = (const float*)d_in[30];
    const float* gru_Wih = (const float*)d_in[31];
    const float* gru_Whh = (const float*)d_in[32];
    const float* gru_bih = (const float*)d_in[33];
    const float* gru_bhh = (const float*)d_in[34];
    const float* ep_Wsrc = (const float*)d_in[35];
    const float* ep_bsrc = (const float*)d_in[36];
    const float* ep_Wdst = (const float*)d_in[37];
    const float* ep_bdst = (const float*)d_in[38];
    const float* ep_Wout = (const float*)d_in[39];
    const float* ep_bout = (const float*)d_in[40];

    float* out     = (float*)d_out;
    float* out_pos = out;
    float* out_neg = out + 512;
    float* out_mem = out + 1024;
    float* out_ts  = out + 1024 + (long)NNODES * D;

    float* ws       = (float*)d_ws;
    float* h1       = ws;                          // NN1*D (reused in-place for next_src)
    float* h_root1  = h1 + (long)NN1 * D;          // GG*D
    float* h_total  = h_root1 + (long)GG * D;      // GG*D
    float* new_mem  = h_total + (long)GG * D;      // 1024*D

    // 1. bulk copy memory/memory_ts -> out (scatter overwrites updated rows later)
    copy_kernel<<<4096, 256, 0, stream>>>((const float4*)memory, (const float4*)memory_ts,
                                          (float4*)out_mem, (float4*)out_ts);
    // 2. layer-1 attention (weights index [1])
    attn_kernel<<<NN1 / 4, 256, 0, stream>>>(
        NN1, dst_feat1, src_feat1, dst_nodes1, src_nodes1, dst_ts1, src_ts1, edge_feat1,
        memory,
        Wq + QDIM * D, bq + D, Wk + KVDIM * D, bk + D, Wv + KVDIM * D, bv + D,
        Wo + 2 * D * D, bo + D, tw + DT, tb + DT,
        nullptr, h1);
    // 3. h_root1 (before e2n clobbers h1)
    hroot_kernel<<<(GG * D + 255) / 256, 256, 0, stream>>>(h1, h_root1);
    // 4. next_src = h1 @ e2n_W + b, in-place
    e2n_kernel<<<NN1 / 4, 256, 0, stream>>>(h1, e2n_W, e2n_b);
    // 5. layer-0 attention, fused h_total = (h0 + h_root1) * 0.5 (weights index [0])
    attn_kernel<<<GG / 4, 256, 0, stream>>>(
        GG, dst_feat0, h1, dst_nodes0, src_nodes0, dst_ts0, src_ts0, edge_feat0,
        memory,
        Wq, bq, Wk, bk, Wv, bv, Wo, bo, tw, tb,
        h_root1, h_total);
    // 6. GRU memory update
    gru_kernel<<<512, 384, 0, stream>>>(dst_nodes0, root_ts, root_edge_feat, memory,
                                        memory_ts, h_total, mt_w, mt_b,
                                        gru_Wih, gru_Whh, gru_bih, gru_bhh, new_mem);
    // 7. scatter (last-occurrence-wins)
    scatter_kernel<<<1024, 128, 0, stream>>>(dst_nodes0, root_ts, new_mem, out_mem, out_ts);
    // 8. edge predictor
    ep_kernel<<<BB / 4, 128, 0, stream>>>(h_total, ep_Wsrc, ep_bsrc, ep_Wdst, ep_bdst,
                                          ep_Wout, ep_bout, out_pos, out_neg);
}